// Round 3
// baseline (224.400 us; speedup 1.0000x reference)
//
#include <hip/hip_runtime.h>
#include <math.h>

#define DM 512
#define NN 512
#define SCALE 651.8986469044033f   // 4096/(2*pi), rounds to same f32 as reference
#define MAGIC 12582912.0f          // 1.5 * 2^23: fma+magic => RNE-rounded integer in mantissa

__device__ __forceinline__ unsigned bf16rne(float f) {
    unsigned u = __float_as_uint(f);
    return (u + 0x7fffu + ((u >> 16) & 1u)) >> 16;
}

// ---------------------------------------------------------------------------
// kprep: three 64x64 LDS-tile transposes, all reads/writes coalesced.
//   packA[d][n] = {SCALE/(1+|W|), B*SCALE + MAGIC}
//   packB[d][n] = {attn_cos, attn_sin}
//   projT[n][d] = {proj_cos_w[d][n], proj_sin_w[d][n]}
// ---------------------------------------------------------------------------
__global__ __launch_bounds__(256) void kprep(
    const float* __restrict__ W, const float* __restrict__ B,
    const float* __restrict__ AC, const float* __restrict__ AS,
    const float* __restrict__ PC, const float* __restrict__ PS,
    float2* __restrict__ packA, float2* __restrict__ packB,
    float2* __restrict__ projT)
{
    __shared__ float2 tile[64][65];
    const int tid = threadIdx.x;
    const int tx = tid & 63, ty = tid >> 6;
    const int r0 = (blockIdx.x >> 3) * 64;   // source row tile
    const int c0 = (blockIdx.x & 7) * 64;    // source col tile

    // ---- phase A: W,B -> packA (src [n][d] -> dst [d][n])
#pragma unroll
    for (int p = 0; p < 16; ++p) {
        int r = p * 4 + ty;
        float w = W[(r0 + r) * DM + c0 + tx];
        float b = B[(r0 + r) * DM + c0 + tx];
        tile[r][tx] = make_float2(SCALE / (1.0f + fabsf(w)), fmaf(b, SCALE, MAGIC));
    }
    __syncthreads();
#pragma unroll
    for (int p = 0; p < 16; ++p) {
        int c = p * 4 + ty;
        packA[(c0 + c) * NN + r0 + tx] = tile[tx][c];
    }
    __syncthreads();

    // ---- phase B: AC,AS -> packB (src [n][d] -> dst [d][n])
#pragma unroll
    for (int p = 0; p < 16; ++p) {
        int r = p * 4 + ty;
        tile[r][tx] = make_float2(AC[(r0 + r) * DM + c0 + tx],
                                  AS[(r0 + r) * DM + c0 + tx]);
    }
    __syncthreads();
#pragma unroll
    for (int p = 0; p < 16; ++p) {
        int c = p * 4 + ty;
        packB[(c0 + c) * NN + r0 + tx] = tile[tx][c];
    }
    __syncthreads();

    // ---- phase C: PC,PS -> projT (src [d][n] -> dst [n][d])
#pragma unroll
    for (int p = 0; p < 16; ++p) {
        int r = p * 4 + ty;
        tile[r][tx] = make_float2(PC[(r0 + r) * NN + c0 + tx],
                                  PS[(r0 + r) * NN + c0 + tx]);
    }
    __syncthreads();
#pragma unroll
    for (int p = 0; p < 16; ++p) {
        int c = p * 4 + ty;
        projT[(c0 + c) * DM + r0 + tx] = tile[tx][c];
    }
}

// ---------------------------------------------------------------------------
// kmain: cos_sum/sin_sum over d via LDS-LUT gathers.
// Block = 512 thr = 8 waves; block owns (8 tokens) x (64 neurons); wave owns
// a 64-wide d-slice. Lane = neuron. Grid = 128 token-tiles x 8 neuron-groups.
// LUT idx: fma with +1.5*2^23 magic -> RNE integer in mantissa, &4095 = mod.
// LUT packed as {sin_bf16 | cos_bf16<<16} -> single random b32 gather/element.
// Cross-wave d-reduction via ds_add_f32 atomics (4 KB).
// ---------------------------------------------------------------------------
__global__ __launch_bounds__(512) void kmain(
    const float* __restrict__ x,
    const float* __restrict__ sinT, const float* __restrict__ cosT,
    const float2* __restrict__ packA, const float2* __restrict__ packB,
    float2* __restrict__ pairs)
{
    __shared__ unsigned lut[4096];   // 16 KB: sin in lo16, cos in hi16 (bf16)
    __shared__ float2 accL[8][64];   // 4 KB:  per-(token, neuron) accumulator

    const int tid  = threadIdx.x;
    const int bid  = blockIdx.x;     // 1024 = 128 tiles * 8 ng
    const int tile = bid >> 3, ng = bid & 7;
    const int lane = tid & 63;
    const int wv   = __builtin_amdgcn_readfirstlane(tid >> 6);  // SGPR -> x loads scalarize
    const int t0   = tile * 8;

#pragma unroll
    for (int j = 0; j < 8; ++j) {
        int k = tid + j * 512;
        lut[k] = bf16rne(sinT[k]) | (bf16rne(cosT[k]) << 16);
    }
    ((float2*)accL)[tid] = make_float2(0.f, 0.f);   // 512 entries == 8*64
    __syncthreads();

    float accC[8], accS[8];
#pragma unroll
    for (int t = 0; t < 8; ++t) { accC[t] = 0.f; accS[t] = 0.f; }

    const float2* pA = packA + (wv * 64) * NN + ng * 64 + lane;
    const float2* pB = packB + (wv * 64) * NN + ng * 64 + lane;
    const float*  xb = x + t0 * DM + wv * 64;

#pragma unroll 2
    for (int i = 0; i < 64; ++i) {
        float2 a  = pA[i * NN];      // {invc, bcMagic} for (n, d)
        float2 w2 = pB[i * NN];      // {attn_cos, attn_sin}
#pragma unroll
        for (int t = 0; t < 8; ++t) {
            float xv = xb[t * DM + i];                 // wave-uniform s_load
            float f  = fmaf(xv, a.x, a.y);             // idx in low mantissa bits
            unsigned u = lut[__float_as_uint(f) & 4095u];
            float cs = __uint_as_float(u & 0xffff0000u);   // cos (bf16->f32)
            float sn = __uint_as_float(u << 16);           // sin (bf16->f32)
            accC[t] = fmaf(cs, w2.x, accC[t]);
            accS[t] = fmaf(sn, w2.y, accS[t]);
        }
    }

#pragma unroll
    for (int t = 0; t < 8; ++t) {
        atomicAdd(&accL[t][lane].x, accC[t]);          // ds_add_f32
        atomicAdd(&accL[t][lane].y, accS[t]);
    }
    __syncthreads();
    {
        int t = tid >> 6, n = tid & 63;
        float2 v = accL[t][n];
        pairs[(t0 + t) * NN + ng * 64 + n] = v;
    }
}

// ---------------------------------------------------------------------------
// kproj: out[t][d] = silu( sum_n cs[t][n]*pc[d][n] + ss[t][n]*ps[d][n] )
// Block = 256 thr: 32 d-quads x 8 tokens; grid = 128 token-tiles x 4 d-groups.
// pairs tile staged in LDS (broadcast reads); projT streamed from L2.
// ---------------------------------------------------------------------------
__global__ __launch_bounds__(256) void kproj(
    const float2* __restrict__ pairs, const float2* __restrict__ projT,
    float* __restrict__ out)
{
    __shared__ float2 pl[8][NN];     // 32 KB: 8 tokens x 512 neurons
    const int bid  = blockIdx.x;     // 512 = 128 tiles * 4 dg
    const int tile = bid >> 2, dg = bid & 3;
    const int tid  = threadIdx.x;
    const int dslot = tid & 31, tg = tid >> 5;
    const int t0   = tile * 8;

    {
        const float4* src = (const float4*)(pairs + t0 * NN);
        float4* dst = (float4*)pl;
#pragma unroll
        for (int k = 0; k < 8; ++k) dst[tid + k * 256] = src[tid + k * 256];  // 2048 f4 = full 32 KB
    }
    __syncthreads();

    const int gslot = dg * 32 + dslot;               // global d-quad 0..127
    const float4* pp = (const float4*)projT + gslot * 2;  // {c,s,c,s} pairs
    float4 acc = make_float4(0.f, 0.f, 0.f, 0.f);
#pragma unroll 4
    for (int n = 0; n < NN; ++n) {
        float4 q0 = pp[n * 256];         // {c[d0],s[d0],c[d1],s[d1]}
        float4 q1 = pp[n * 256 + 1];     // {c[d2],s[d2],c[d3],s[d3]}
        float2 cs = pl[tg][n];
        acc.x = fmaf(q0.x, cs.x, acc.x); acc.x = fmaf(q0.y, cs.y, acc.x);
        acc.y = fmaf(q0.z, cs.x, acc.y); acc.y = fmaf(q0.w, cs.y, acc.y);
        acc.z = fmaf(q1.x, cs.x, acc.z); acc.z = fmaf(q1.y, cs.y, acc.z);
        acc.w = fmaf(q1.z, cs.x, acc.w); acc.w = fmaf(q1.w, cs.y, acc.w);
    }
    float4 o;
    o.x = acc.x / (1.f + __expf(-acc.x));
    o.y = acc.y / (1.f + __expf(-acc.y));
    o.z = acc.z / (1.f + __expf(-acc.z));
    o.w = acc.w / (1.f + __expf(-acc.w));
    *(float4*)(out + (t0 + tg) * DM + gslot * 4) = o;
}

// ---------------------------------------------------------------------------
extern "C" void kernel_launch(void* const* d_in, const int* in_sizes, int n_in,
                              void* d_out, int out_size, void* d_ws, size_t ws_size,
                              hipStream_t stream)
{
    const float* x    = (const float*)d_in[0];
    const float* W    = (const float*)d_in[1];
    const float* B    = (const float*)d_in[2];
    const float* AC   = (const float*)d_in[3];
    const float* AS   = (const float*)d_in[4];
    const float* PC   = (const float*)d_in[5];
    const float* PS   = (const float*)d_in[6];
    const float* sinT = (const float*)d_in[7];
    const float* cosT = (const float*)d_in[8];
    float* out = (float*)d_out;

    char* ws = (char*)d_ws;
    float2* packA = (float2*)ws;                   // 2 MiB [d][n] {invc, bcMagic}
    float2* packB = (float2*)(ws + (2u << 20));    // 2 MiB [d][n] {ac, as}
    float2* projT = (float2*)(ws + (4u << 20));    // 2 MiB [n][d] {pc, ps}
    float2* pairs = (float2*)(ws + (6u << 20));    // 4 MiB [token][n] {cs, ss}

    kprep<<<64, 256, 0, stream>>>(W, B, AC, AS, PC, PS, packA, packB, projT);
    kmain<<<1024, 512, 0, stream>>>(x, sinT, cosT, packA, packB, pairs);
    kproj<<<512, 256, 0, stream>>>(pairs, projT, out);
}